// Round 1
// baseline (972.285 us; speedup 1.0000x reference)
//
#include <hip/hip_runtime.h>
#include <cstdint>
#include <cstddef>

#define NN 100000
#define IN_CH 165
#define KP0 168
#define HID 128

// ---------------- utility ----------------
__global__ void k_zero_i32(int* __restrict__ p, int n) {
    int i = blockIdx.x * blockDim.x + threadIdx.x;
    if (i < n) p[i] = 0;
}

// ---------------- CSR build ----------------
__global__ void k_hist(const int* __restrict__ dst, int E, int* __restrict__ deg) {
    int i = blockIdx.x * blockDim.x + threadIdx.x;
    if (i < E) atomicAdd(&deg[dst[i]], 1);
}

#define SCAN_CH 512
__global__ void k_scan1(const int* __restrict__ deg, int N, int* __restrict__ part) {
    __shared__ int sd[SCAN_CH];
    int t = threadIdx.x;
    int i = blockIdx.x * SCAN_CH + t;
    sd[t] = (i < N) ? deg[i] : 0;
    __syncthreads();
    for (int off = SCAN_CH / 2; off > 0; off >>= 1) {
        if (t < off) sd[t] += sd[t + off];
        __syncthreads();
    }
    if (t == 0) part[blockIdx.x] = sd[0];
}

__global__ void k_scan2(int* __restrict__ part, int nb) {
    __shared__ int sd[1024];
    int t = threadIdx.x;
    int v = (t < nb) ? part[t] : 0;
    sd[t] = v;
    __syncthreads();
    for (int off = 1; off < 1024; off <<= 1) {
        int x = (t >= off) ? sd[t - off] : 0;
        __syncthreads();
        sd[t] += x;
        __syncthreads();
    }
    if (t < nb) part[t] = sd[t] - v;  // exclusive scan of block sums
}

__global__ void k_scan3(const int* __restrict__ deg, const int* __restrict__ part,
                        int N, int E, int* __restrict__ row_off,
                        int* __restrict__ pos, float* __restrict__ inv) {
    __shared__ int sd[SCAN_CH];
    int t = threadIdx.x;
    int i = blockIdx.x * SCAN_CH + t;
    int v = (i < N) ? deg[i] : 0;
    sd[t] = v;
    __syncthreads();
    for (int off = 1; off < SCAN_CH; off <<= 1) {
        int x = (t >= off) ? sd[t - off] : 0;
        __syncthreads();
        sd[t] += x;
        __syncthreads();
    }
    int excl = sd[t] - v + part[blockIdx.x];
    if (i < N) {
        row_off[i] = excl;
        pos[i] = excl;                 // note: pos aliases deg; read-before-write per thread
        inv[i] = 1.0f / (float)max(v, 1);
    }
    if (i == N - 1) row_off[N] = E;
}

__global__ void k_fill(const int* __restrict__ src, const int* __restrict__ dst,
                       int E, int* __restrict__ pos, int* __restrict__ csr_src) {
    int i = blockIdx.x * blockDim.x + threadIdx.x;
    if (i < E) {
        int p = atomicAdd(&pos[dst[i]], 1);
        csr_src[p] = src[i];
    }
}

// ---------------- weight transpose+pad: Wt[k*HID + j] = W[j*K + k] (k<KP, zero pad) --------
__global__ void k_wt(const float* __restrict__ W, int K, int KP, float* __restrict__ Wt) {
    int idx = blockIdx.x * blockDim.x + threadIdx.x;
    if (idx < KP * HID) {
        int k = idx >> 7;
        int j = idx & 127;
        Wt[idx] = (k < K) ? W[j * K + k] : 0.0f;
    }
}

// ---------------- fused dual GEMM: yl = h @ Wl^T, yr = h @ Wr^T ----------------
// 16 rows per block, 128 threads (thread j = output column j), weights pre-transposed [KP][128]
template <int K, int KP>
__global__ __launch_bounds__(128) void k_gemm2(const float* __restrict__ h,
                                               const float* __restrict__ Wlt,
                                               const float* __restrict__ Wrt,
                                               float* __restrict__ yl,
                                               float* __restrict__ yr, int N) {
    __shared__ __align__(16) float hs[16 * KP];
    const int tid = threadIdx.x;
    const int node0 = blockIdx.x * 16;
    if (node0 >= N) return;

    // stage 16 rows of h into LDS (rows padded to KP)
    const float* hp = h + (size_t)node0 * K;
    for (int idx = tid; idx < 16 * K; idx += 128) {
        int r = idx / K;
        int c = idx - r * K;
        hs[r * KP + c] = hp[idx];
    }
    if (K < KP) {
        for (int idx = tid; idx < 16 * (KP - K); idx += 128) {
            int r = idx / (KP - K);
            int c = idx - r * (KP - K);
            hs[r * KP + K + c] = 0.0f;
        }
    }
    __syncthreads();

    float accl[16], accr[16];
#pragma unroll
    for (int r = 0; r < 16; r++) { accl[r] = 0.0f; accr[r] = 0.0f; }

    const int j = tid;
    for (int k = 0; k < KP; k += 4) {
        float wl0 = Wlt[(k + 0) * HID + j];
        float wl1 = Wlt[(k + 1) * HID + j];
        float wl2 = Wlt[(k + 2) * HID + j];
        float wl3 = Wlt[(k + 3) * HID + j];
        float wr0 = Wrt[(k + 0) * HID + j];
        float wr1 = Wrt[(k + 1) * HID + j];
        float wr2 = Wrt[(k + 2) * HID + j];
        float wr3 = Wrt[(k + 3) * HID + j];
#pragma unroll
        for (int r = 0; r < 16; r++) {
            const float4 hv = *reinterpret_cast<const float4*>(&hs[r * KP + k]);
            accl[r] = fmaf(hv.w, wl3, fmaf(hv.z, wl2, fmaf(hv.y, wl1, fmaf(hv.x, wl0, accl[r]))));
            accr[r] = fmaf(hv.w, wr3, fmaf(hv.z, wr2, fmaf(hv.y, wr1, fmaf(hv.x, wr0, accr[r]))));
        }
    }

#pragma unroll
    for (int r = 0; r < 16; r++) {
        yl[(size_t)(node0 + r) * HID + j] = accl[r];
        yr[(size_t)(node0 + r) * HID + j] = accr[r];
    }
}

// ---------------- aggregate + combine (in place over yr) ----------------
// h_next[dst][j] = relu( (sum_{src in N(dst)} yl[src][j]) * inv[dst] + bias[j] + yr[dst][j] )
template <bool RELU>
__global__ __launch_bounds__(256) void k_agg(const float* __restrict__ yl,
                                             const int* __restrict__ row_off,
                                             const int* __restrict__ csr_src,
                                             const float* __restrict__ inv,
                                             const float* __restrict__ bias,
                                             float* __restrict__ yr_io, int N) {
    int node = blockIdx.x * 2 + (threadIdx.x >> 7);
    int j = threadIdx.x & 127;
    if (node >= N) return;
    int beg = row_off[node];
    int end = row_off[node + 1];
    float a0 = 0.f, a1 = 0.f, a2 = 0.f, a3 = 0.f;
    int e = beg;
    for (; e + 4 <= end; e += 4) {
        int s0 = csr_src[e + 0];
        int s1 = csr_src[e + 1];
        int s2 = csr_src[e + 2];
        int s3 = csr_src[e + 3];
        a0 += yl[(size_t)s0 * HID + j];
        a1 += yl[(size_t)s1 * HID + j];
        a2 += yl[(size_t)s2 * HID + j];
        a3 += yl[(size_t)s3 * HID + j];
    }
    for (; e < end; ++e) a0 += yl[(size_t)csr_src[e] * HID + j];
    float v = (a0 + a1 + a2 + a3) * inv[node] + bias[j] + yr_io[(size_t)node * HID + j];
    if (RELU) v = fmaxf(v, 0.0f);
    yr_io[(size_t)node * HID + j] = v;
}

// ---------------- output head: out[n][c] = h[n][:] . W_out[c][:] + b_out[c] ----------------
__global__ __launch_bounds__(256) void k_out(const float* __restrict__ h,
                                             const float* __restrict__ Wout,
                                             const float* __restrict__ bout,
                                             float* __restrict__ out, int N) {
    int wave = threadIdx.x >> 6;
    int lane = threadIdx.x & 63;
    int node = blockIdx.x * 4 + wave;
    if (node >= N) return;
    float h0 = h[(size_t)node * HID + lane];
    float h1 = h[(size_t)node * HID + 64 + lane];
    float p0 = h0 * Wout[lane] + h1 * Wout[64 + lane];
    float p1 = h0 * Wout[128 + lane] + h1 * Wout[192 + lane];
    for (int off = 32; off > 0; off >>= 1) {
        p0 += __shfl_xor(p0, off);
        p1 += __shfl_xor(p1, off);
    }
    if (lane == 0) {
        out[(size_t)node * 2 + 0] = p0 + bout[0];
        out[(size_t)node * 2 + 1] = p1 + bout[1];
    }
}

extern "C" void kernel_launch(void* const* d_in, const int* in_sizes, int n_in,
                              void* d_out, int out_size, void* d_ws, size_t ws_size,
                              hipStream_t stream) {
    const float* x    = (const float*)d_in[0];
    const int*   ei   = (const int*)d_in[1];
    const float* Wl0  = (const float*)d_in[2];
    const float* bl0  = (const float*)d_in[3];
    const float* Wr0  = (const float*)d_in[4];
    const float* Wl1  = (const float*)d_in[5];
    const float* bl1  = (const float*)d_in[6];
    const float* Wr1  = (const float*)d_in[7];
    const float* Wl2  = (const float*)d_in[8];
    const float* bl2  = (const float*)d_in[9];
    const float* Wr2  = (const float*)d_in[10];
    const float* Wout = (const float*)d_in[11];
    const float* bout = (const float*)d_in[12];

    const int N = NN;
    const int E = in_sizes[1] / 2;
    const int* src = ei;
    const int* dst = ei + E;

    // workspace carve-up (256B aligned)
    char* w = (char*)d_ws;
    auto alloc = [&](size_t bytes) {
        char* p = w;
        w += (bytes + 255) & ~(size_t)255;
        return p;
    };
    int*   pos     = (int*)alloc((size_t)N * 4);        // doubles as deg
    int*   row_off = (int*)alloc((size_t)(N + 1) * 4);
    float* inv     = (float*)alloc((size_t)N * 4);
    int*   part    = (int*)alloc(1024 * 4);
    int*   csr     = (int*)alloc((size_t)E * 4);
    float* Wl0t    = (float*)alloc((size_t)KP0 * HID * 4);
    float* Wr0t    = (float*)alloc((size_t)KP0 * HID * 4);
    float* Wl1t    = (float*)alloc((size_t)HID * HID * 4);
    float* Wr1t    = (float*)alloc((size_t)HID * HID * 4);
    float* Wl2t    = (float*)alloc((size_t)HID * HID * 4);
    float* Wr2t    = (float*)alloc((size_t)HID * HID * 4);
    float* B0      = (float*)alloc((size_t)N * HID * 4);
    float* B1      = (float*)alloc((size_t)N * HID * 4);
    float* B2      = (float*)alloc((size_t)N * HID * 4);

    const int nb = (N + SCAN_CH - 1) / SCAN_CH;

    // ---- CSR build ----
    k_zero_i32<<<(N + 255) / 256, 256, 0, stream>>>(pos, N);
    k_hist<<<(E + 255) / 256, 256, 0, stream>>>(dst, E, pos);
    k_scan1<<<nb, SCAN_CH, 0, stream>>>(pos, N, part);
    k_scan2<<<1, 1024, 0, stream>>>(part, nb);
    k_scan3<<<nb, SCAN_CH, 0, stream>>>(pos, part, N, E, row_off, pos, inv);
    k_fill<<<(E + 255) / 256, 256, 0, stream>>>(src, dst, E, pos, csr);

    // ---- weight transpose+pad ----
    k_wt<<<(KP0 * HID + 255) / 256, 256, 0, stream>>>(Wl0, IN_CH, KP0, Wl0t);
    k_wt<<<(KP0 * HID + 255) / 256, 256, 0, stream>>>(Wr0, IN_CH, KP0, Wr0t);
    k_wt<<<(HID * HID + 255) / 256, 256, 0, stream>>>(Wl1, HID, HID, Wl1t);
    k_wt<<<(HID * HID + 255) / 256, 256, 0, stream>>>(Wr1, HID, HID, Wr1t);
    k_wt<<<(HID * HID + 255) / 256, 256, 0, stream>>>(Wl2, HID, HID, Wl2t);
    k_wt<<<(HID * HID + 255) / 256, 256, 0, stream>>>(Wr2, HID, HID, Wr2t);

    const int gemm_grid = N / 16;           // N divisible by 16
    const int agg_grid = (N + 1) / 2;

    // ---- layer 0: h = x (K=165) ----
    k_gemm2<IN_CH, KP0><<<gemm_grid, 128, 0, stream>>>(x, Wl0t, Wr0t, B0, B1, N);
    k_agg<true><<<agg_grid, 256, 0, stream>>>(B0, row_off, csr, inv, bl0, B1, N);

    // ---- layer 1: h = B1 ----
    k_gemm2<HID, HID><<<gemm_grid, 128, 0, stream>>>(B1, Wl1t, Wr1t, B0, B2, N);
    k_agg<true><<<agg_grid, 256, 0, stream>>>(B0, row_off, csr, inv, bl1, B2, N);

    // ---- layer 2: h = B2 ----
    k_gemm2<HID, HID><<<gemm_grid, 128, 0, stream>>>(B2, Wl2t, Wr2t, B0, B1, N);
    k_agg<false><<<agg_grid, 256, 0, stream>>>(B0, row_off, csr, inv, bl2, B1, N);

    // ---- output head ----
    k_out<<<(N + 3) / 4, 256, 0, stream>>>(B1, Wout, bout, (float*)d_out, N);
}

// Round 2
// 692.283 us; speedup vs baseline: 1.4045x; 1.4045x over previous
//
#include <hip/hip_runtime.h>
#include <cstdint>
#include <cstddef>

#define NN 100000
#define IN_CH 165
#define HID 128

typedef __attribute__((ext_vector_type(8))) short short8;
typedef __attribute__((ext_vector_type(4))) float f32x4;

__device__ __forceinline__ ushort f2bf(float v) {
    uint b = __builtin_bit_cast(uint, v);
    return (ushort)((b + 0x7FFFu + ((b >> 16) & 1u)) >> 16);
}
__device__ __forceinline__ float bf2f(ushort u) {
    uint b = ((uint)u) << 16;
    return __builtin_bit_cast(float, b);
}

// ---------------- utility ----------------
__global__ void k_zero_i32(int* __restrict__ p, int n) {
    int i = blockIdx.x * blockDim.x + threadIdx.x;
    if (i < n) p[i] = 0;
}

// ---------------- CSR build ----------------
__global__ void k_hist(const int* __restrict__ dst, int E, int* __restrict__ deg) {
    int i = blockIdx.x * blockDim.x + threadIdx.x;
    if (i < E) atomicAdd(&deg[dst[i]], 1);
}

#define SCAN_CH 512
__global__ void k_scan1(const int* __restrict__ deg, int N, int* __restrict__ part) {
    __shared__ int sd[SCAN_CH];
    int t = threadIdx.x;
    int i = blockIdx.x * SCAN_CH + t;
    sd[t] = (i < N) ? deg[i] : 0;
    __syncthreads();
    for (int off = SCAN_CH / 2; off > 0; off >>= 1) {
        if (t < off) sd[t] += sd[t + off];
        __syncthreads();
    }
    if (t == 0) part[blockIdx.x] = sd[0];
}

__global__ void k_scan2(int* __restrict__ part, int nb) {
    __shared__ int sd[1024];
    int t = threadIdx.x;
    int v = (t < nb) ? part[t] : 0;
    sd[t] = v;
    __syncthreads();
    for (int off = 1; off < 1024; off <<= 1) {
        int x = (t >= off) ? sd[t - off] : 0;
        __syncthreads();
        sd[t] += x;
        __syncthreads();
    }
    if (t < nb) part[t] = sd[t] - v;  // exclusive scan of block sums
}

__global__ void k_scan3(const int* __restrict__ deg, const int* __restrict__ part,
                        int N, int E, int* __restrict__ row_off,
                        int* __restrict__ pos, float* __restrict__ inv) {
    __shared__ int sd[SCAN_CH];
    int t = threadIdx.x;
    int i = blockIdx.x * SCAN_CH + t;
    int v = (i < N) ? deg[i] : 0;
    sd[t] = v;
    __syncthreads();
    for (int off = 1; off < SCAN_CH; off <<= 1) {
        int x = (t >= off) ? sd[t - off] : 0;
        __syncthreads();
        sd[t] += x;
        __syncthreads();
    }
    int excl = sd[t] - v + part[blockIdx.x];
    if (i < N) {
        row_off[i] = excl;
        pos[i] = excl;                 // pos aliases deg; read-before-write per thread
        inv[i] = 1.0f / (float)max(v, 1);
    }
    if (i == N - 1) row_off[N] = E;
}

__global__ void k_fill(const int* __restrict__ src, const int* __restrict__ dst,
                       int E, int* __restrict__ pos, int* __restrict__ csr_src) {
    int i = blockIdx.x * blockDim.x + threadIdx.x;
    if (i < E) {
        int p = atomicAdd(&pos[dst[i]], 1);
        csr_src[p] = src[i];
    }
}

// ---------------- weight pack: W[j][k] (row-major [128][K]) -> k-blocked bf16 hi/lo
// out[(k>>3)*1024 + j*8 + (k&7)], zero-padded to KP
__global__ void k_wpack(const float* __restrict__ W, int K, int KP,
                        ushort* __restrict__ Wh, ushort* __restrict__ Wl) {
    int idx = blockIdx.x * blockDim.x + threadIdx.x;
    if (idx >= KP * HID) return;
    int k = idx / HID;
    int j = idx - k * HID;
    float v = (k < K) ? W[j * K + k] : 0.0f;
    ushort h = f2bf(v);
    ushort l = f2bf(v - bf2f(h));
    int o = (k >> 3) * (HID * 8) + j * 8 + (k & 7);
    Wh[o] = h;
    Wl[o] = l;
}

// ---------------- MFMA dual GEMM (bf16x3 split fp32): yl = h @ Wl^T, yr = h @ Wr^T
// 32 nodes/block, 256 threads (4 waves). Wave w: mat = w&1, col-blocks (w>>1)*4 .. +3.
// A staged in LDS as bf16 hi/lo, row-major with XOR swizzle byte ^= (row&7)<<4.
template <int K, int KP>
__global__ __launch_bounds__(256) void k_gemm_mfma(
    const float* __restrict__ h,
    const ushort* __restrict__ Wlh, const ushort* __restrict__ Wll,
    const ushort* __restrict__ Wrh, const ushort* __restrict__ Wrl,
    float* __restrict__ yl, float* __restrict__ yr)
{
    constexpr int RS = KP * 2;  // LDS row stride (bytes)
    __shared__ __align__(16) char Ah[32 * RS];
    __shared__ __align__(16) char Al[32 * RS];
    const int tid = threadIdx.x;
    const int node0 = blockIdx.x * 32;
    const float* __restrict__ hp = h + (size_t)node0 * K;

    // ---- stage + split-convert 32 x K tile ----
    constexpr int Q = 32 * (KP / 4);
    for (int q = tid; q < Q; q += 256) {
        const int r = q / (KP / 4);
        const int kp = (q - r * (KP / 4)) * 4;
        float v0, v1, v2, v3;
        if constexpr (K % 4 == 0) {
            const float4 v = *reinterpret_cast<const float4*>(&hp[r * K + kp]);
            v0 = v.x; v1 = v.y; v2 = v.z; v3 = v.w;
        } else {
            v0 = (kp + 0 < K) ? hp[r * K + kp + 0] : 0.0f;
            v1 = (kp + 1 < K) ? hp[r * K + kp + 1] : 0.0f;
            v2 = (kp + 2 < K) ? hp[r * K + kp + 2] : 0.0f;
            v3 = (kp + 3 < K) ? hp[r * K + kp + 3] : 0.0f;
        }
        const ushort h0 = f2bf(v0), h1 = f2bf(v1), h2 = f2bf(v2), h3 = f2bf(v3);
        const ushort l0 = f2bf(v0 - bf2f(h0)), l1 = f2bf(v1 - bf2f(h1));
        const ushort l2 = f2bf(v2 - bf2f(h2)), l3 = f2bf(v3 - bf2f(h3));
        const int byte = r * RS + ((kp * 2) ^ ((r & 7) << 4));
        *reinterpret_cast<ushort4*>(Ah + byte) = make_ushort4(h0, h1, h2, h3);
        *reinterpret_cast<ushort4*>(Al + byte) = make_ushort4(l0, l1, l2, l3);
    }
    __syncthreads();

    // ---- MFMA phase ----
    const int lane = tid & 63;
    const int w = tid >> 6;
    const int trow = lane & 15;   // A row within tile / D col within tile
    const int kg = lane >> 4;     // k-group
    const ushort* __restrict__ Bh = (w & 1) ? Wrh : Wlh;
    const ushort* __restrict__ Bl = (w & 1) ? Wrl : Wll;
    float* __restrict__ yo = (w & 1) ? yr : yl;
    const int cb0 = (w >> 1) * 4;

    f32x4 acc[2][4];
#pragma unroll
    for (int a = 0; a < 2; ++a)
#pragma unroll
        for (int b = 0; b < 4; ++b) acc[a][b] = (f32x4){0.f, 0.f, 0.f, 0.f};

    const int xo = (trow & 7) << 4;
    const char* __restrict__ pA0 = Ah + trow * RS;
    const char* __restrict__ pA1 = Ah + (trow + 16) * RS;
    const char* __restrict__ pL0 = Al + trow * RS;
    const char* __restrict__ pL1 = Al + (trow + 16) * RS;

    constexpr int KS = KP / 32;
    for (int ks = 0; ks < KS; ++ks) {
        const int kbyte = (ks * 64 + kg * 16) ^ xo;
        const short8 a0h = *reinterpret_cast<const short8*>(pA0 + kbyte);
        const short8 a0l = *reinterpret_cast<const short8*>(pL0 + kbyte);
        const short8 a1h = *reinterpret_cast<const short8*>(pA1 + kbyte);
        const short8 a1l = *reinterpret_cast<const short8*>(pL1 + kbyte);
        const int bbase = (ks * 4 + kg) * (HID * 8) + trow * 8;
#pragma unroll
        for (int ci = 0; ci < 4; ++ci) {
            const int bo = bbase + (cb0 + ci) * 128;
            const short8 bh = *reinterpret_cast<const short8*>(Bh + bo);
            const short8 bl = *reinterpret_cast<const short8*>(Bl + bo);
            acc[0][ci] = __builtin_amdgcn_mfma_f32_16x16x32_bf16(a0l, bh, acc[0][ci], 0, 0, 0);
            acc[0][ci] = __builtin_amdgcn_mfma_f32_16x16x32_bf16(a0h, bl, acc[0][ci], 0, 0, 0);
            acc[0][ci] = __builtin_amdgcn_mfma_f32_16x16x32_bf16(a0h, bh, acc[0][ci], 0, 0, 0);
            acc[1][ci] = __builtin_amdgcn_mfma_f32_16x16x32_bf16(a1l, bh, acc[1][ci], 0, 0, 0);
            acc[1][ci] = __builtin_amdgcn_mfma_f32_16x16x32_bf16(a1h, bl, acc[1][ci], 0, 0, 0);
            acc[1][ci] = __builtin_amdgcn_mfma_f32_16x16x32_bf16(a1h, bh, acc[1][ci], 0, 0, 0);
        }
    }

    // ---- epilogue: D col = lane&15, row = (lane>>4)*4 + reg ----
#pragma unroll
    for (int rb = 0; rb < 2; ++rb) {
        const int nb_ = node0 + rb * 16 + kg * 4;
#pragma unroll
        for (int ci = 0; ci < 4; ++ci) {
            const int col = (cb0 + ci) * 16 + trow;
            const f32x4 a = acc[rb][ci];
#pragma unroll
            for (int rr = 0; rr < 4; ++rr)
                yo[(size_t)(nb_ + rr) * HID + col] = a[rr];
        }
    }
}

// ---------------- aggregate + combine; wave per node, float2 per lane ----------------
// HEAD=0: h_next = relu(sum*inv + bias + yr)  (written to outp as [N][128])
// HEAD=1: v = sum*inv + bias + yr; out[n][c] = sum_j v_j * Wout[c][j] + bout[c]
template <int HEAD>
__global__ __launch_bounds__(256) void k_agg2(
    const float* __restrict__ yl, const int* __restrict__ row_off,
    const int* __restrict__ csr, const float* __restrict__ inv,
    const float* __restrict__ bias, const float* __restrict__ yr,
    float* __restrict__ outp, const float* __restrict__ Wout,
    const float* __restrict__ bout, int N)
{
    const int wid = (blockIdx.x * 256 + (int)threadIdx.x) >> 6;
    const int lane = threadIdx.x & 63;
    if (wid >= N) return;
    const int beg = row_off[wid];
    const int end = row_off[wid + 1];
    const float2* __restrict__ Y = (const float2*)yl;
    float ax0 = 0.f, ay0 = 0.f, ax1 = 0.f, ay1 = 0.f;
    float ax2 = 0.f, ay2 = 0.f, ax3 = 0.f, ay3 = 0.f;
    int e = beg;
    for (; e + 4 <= end; e += 4) {
        const int s0 = csr[e + 0], s1 = csr[e + 1], s2 = csr[e + 2], s3 = csr[e + 3];
        const float2 v0 = Y[(size_t)s0 * 64 + lane];
        const float2 v1 = Y[(size_t)s1 * 64 + lane];
        const float2 v2 = Y[(size_t)s2 * 64 + lane];
        const float2 v3 = Y[(size_t)s3 * 64 + lane];
        ax0 += v0.x; ay0 += v0.y;
        ax1 += v1.x; ay1 += v1.y;
        ax2 += v2.x; ay2 += v2.y;
        ax3 += v3.x; ay3 += v3.y;
    }
    for (; e < end; ++e) {
        const float2 v = Y[(size_t)csr[e] * 64 + lane];
        ax0 += v.x; ay0 += v.y;
    }
    const float iv = inv[wid];
    const float2 r = ((const float2*)yr)[(size_t)wid * 64 + lane];
    const float2 b = ((const float2*)bias)[lane];
    float vx = (ax0 + ax1 + ax2 + ax3) * iv + b.x + r.x;
    float vy = (ay0 + ay1 + ay2 + ay3) * iv + b.y + r.y;
    if constexpr (!HEAD) {
        vx = fmaxf(vx, 0.0f);
        vy = fmaxf(vy, 0.0f);
        ((float2*)outp)[(size_t)wid * 64 + lane] = make_float2(vx, vy);
    } else {
        float p0 = vx * Wout[2 * lane] + vy * Wout[2 * lane + 1];
        float p1 = vx * Wout[128 + 2 * lane] + vy * Wout[129 + 2 * lane];
#pragma unroll
        for (int off = 32; off > 0; off >>= 1) {
            p0 += __shfl_xor(p0, off);
            p1 += __shfl_xor(p1, off);
        }
        if (lane == 0) {
            outp[(size_t)wid * 2 + 0] = p0 + bout[0];
            outp[(size_t)wid * 2 + 1] = p1 + bout[1];
        }
    }
}

extern "C" void kernel_launch(void* const* d_in, const int* in_sizes, int n_in,
                              void* d_out, int out_size, void* d_ws, size_t ws_size,
                              hipStream_t stream) {
    const float* x    = (const float*)d_in[0];
    const int*   ei   = (const int*)d_in[1];
    const float* Wl0  = (const float*)d_in[2];
    const float* bl0  = (const float*)d_in[3];
    const float* Wr0  = (const float*)d_in[4];
    const float* Wl1  = (const float*)d_in[5];
    const float* bl1  = (const float*)d_in[6];
    const float* Wr1  = (const float*)d_in[7];
    const float* Wl2  = (const float*)d_in[8];
    const float* bl2  = (const float*)d_in[9];
    const float* Wr2  = (const float*)d_in[10];
    const float* Wout = (const float*)d_in[11];
    const float* bout = (const float*)d_in[12];

    const int N = NN;
    const int E = in_sizes[1] / 2;
    const int* src = ei;
    const int* dst = ei + E;

    // workspace carve-up (256B aligned)
    char* w = (char*)d_ws;
    auto alloc = [&](size_t bytes) {
        char* p = w;
        w += (bytes + 255) & ~(size_t)255;
        return p;
    };
    int*    pos     = (int*)alloc((size_t)N * 4);  // doubles as deg
    int*    row_off = (int*)alloc((size_t)(N + 1) * 4);
    float*  inv     = (float*)alloc((size_t)N * 4);
    int*    part    = (int*)alloc(1024 * 4);
    int*    csr     = (int*)alloc((size_t)E * 4);
    ushort* Wl0h    = (ushort*)alloc((size_t)192 * HID * 2);
    ushort* Wl0l    = (ushort*)alloc((size_t)192 * HID * 2);
    ushort* Wr0h    = (ushort*)alloc((size_t)192 * HID * 2);
    ushort* Wr0l    = (ushort*)alloc((size_t)192 * HID * 2);
    ushort* Wl1h    = (ushort*)alloc((size_t)HID * HID * 2);
    ushort* Wl1l    = (ushort*)alloc((size_t)HID * HID * 2);
    ushort* Wr1h    = (ushort*)alloc((size_t)HID * HID * 2);
    ushort* Wr1l    = (ushort*)alloc((size_t)HID * HID * 2);
    ushort* Wl2h    = (ushort*)alloc((size_t)HID * HID * 2);
    ushort* Wl2l    = (ushort*)alloc((size_t)HID * HID * 2);
    ushort* Wr2h    = (ushort*)alloc((size_t)HID * HID * 2);
    ushort* Wr2l    = (ushort*)alloc((size_t)HID * HID * 2);
    float*  B0      = (float*)alloc((size_t)N * HID * 4);
    float*  B1      = (float*)alloc((size_t)N * HID * 4);
    float*  B2      = (float*)alloc((size_t)N * HID * 4);

    const int nb = (N + SCAN_CH - 1) / SCAN_CH;

    // ---- CSR build ----
    k_zero_i32<<<(N + 255) / 256, 256, 0, stream>>>(pos, N);
    k_hist<<<(E + 255) / 256, 256, 0, stream>>>(dst, E, pos);
    k_scan1<<<nb, SCAN_CH, 0, stream>>>(pos, N, part);
    k_scan2<<<1, 1024, 0, stream>>>(part, nb);
    k_scan3<<<nb, SCAN_CH, 0, stream>>>(pos, part, N, E, row_off, pos, inv);
    k_fill<<<(E + 255) / 256, 256, 0, stream>>>(src, dst, E, pos, csr);

    // ---- weight packing (bf16 hi/lo, k-blocked) ----
    k_wpack<<<(192 * HID + 255) / 256, 256, 0, stream>>>(Wl0, IN_CH, 192, Wl0h, Wl0l);
    k_wpack<<<(192 * HID + 255) / 256, 256, 0, stream>>>(Wr0, IN_CH, 192, Wr0h, Wr0l);
    k_wpack<<<(HID * HID + 255) / 256, 256, 0, stream>>>(Wl1, HID, HID, Wl1h, Wl1l);
    k_wpack<<<(HID * HID + 255) / 256, 256, 0, stream>>>(Wr1, HID, HID, Wr1h, Wr1l);
    k_wpack<<<(HID * HID + 255) / 256, 256, 0, stream>>>(Wl2, HID, HID, Wl2h, Wl2l);
    k_wpack<<<(HID * HID + 255) / 256, 256, 0, stream>>>(Wr2, HID, HID, Wr2h, Wr2l);

    const int gemm_grid = N / 32;   // 3125
    const int agg_grid = N / 4;     // 25000

    // ---- layer 0: h = x (K=165, pad 192) ----
    k_gemm_mfma<IN_CH, 192><<<gemm_grid, 256, 0, stream>>>(x, Wl0h, Wl0l, Wr0h, Wr0l, B0, B1);
    k_agg2<0><<<agg_grid, 256, 0, stream>>>(B0, row_off, csr, inv, bl0, B1, B1, nullptr, nullptr, N);

    // ---- layer 1 ----
    k_gemm_mfma<HID, HID><<<gemm_grid, 256, 0, stream>>>(B1, Wl1h, Wl1l, Wr1h, Wr1l, B0, B2);
    k_agg2<0><<<agg_grid, 256, 0, stream>>>(B0, row_off, csr, inv, bl1, B2, B2, nullptr, nullptr, N);

    // ---- layer 2 + fused output head ----
    k_gemm_mfma<HID, HID><<<gemm_grid, 256, 0, stream>>>(B2, Wl2h, Wl2l, Wr2h, Wr2l, B0, B1);
    k_agg2<1><<<agg_grid, 256, 0, stream>>>(B0, row_off, csr, inv, bl2, B1, (float*)d_out, Wout, bout, N);
}